// Round 2
// baseline (45.545 us; speedup 1.0000x reference)
//
#include <hip/hip_runtime.h>

#define ROWS 64
#define HSTRIDE 93   // odd stride -> only 2-way LDS aliasing on phase-2 reads (free)
#define LMAX 92      // only h[0..91] can reach the output
#define TCOLS 400

__device__ __forceinline__ float tanh_fast(float z) {
    const float ez = __expf(2.0f * z);
    return 1.0f - 2.0f / (ez + 1.0f);
}

__global__ __launch_bounds__(256) void pde_fused_v2_kernel(
    const float* __restrict__ x,        // (B, 400)
    const float* __restrict__ wh_rec,   // (1,2)
    const float* __restrict__ wx_rec,   // (2,2)
    const float* __restrict__ wx_eval,  // (2,2)
    const float* __restrict__ wh_eval,  // (2,)
    const float* __restrict__ b_eval,   // (2,)
    const float* __restrict__ conv_w,   // (3,3,4) [o][ch][k]
    const float* __restrict__ conv_b,   // (3,)
    const float* __restrict__ fc_w,     // (3,12)
    const float* __restrict__ fc_b,     // (3,)
    float* __restrict__ out,            // (B, 3)
    long long Btot)
{
    __shared__ float hlds[ROWS * HSTRIDE];
    const int tid = threadIdx.x;
    const long long r0 = (long long)blockIdx.x * ROWS;

    // ---- Phase 1: coalesced x load, 4->1 mean into LDS ----
    if (r0 + ROWS <= Btot) {
        // full tile: no per-lane guard; keep a few loads in flight
#pragma unroll 4
        for (int k = 0; k < (ROWS * LMAX) / 256; k++) {
            const int i = tid + k * 256;
            const int r = i / LMAX;
            const int l = i - r * LMAX;
            const float4 xv = *reinterpret_cast<const float4*>(x + (r0 + r) * TCOLS + l * 4);
            hlds[r * HSTRIDE + l] = (xv.x + xv.y + xv.z + xv.w) * 0.25f;
        }
    } else {
        for (int i = tid; i < ROWS * LMAX; i += 256) {
            const int r = i / LMAX;
            const int l = i - r * LMAX;
            if (r0 + r < Btot) {
                const float4 xv = *reinterpret_cast<const float4*>(x + (r0 + r) * TCOLS + l * 4);
                hlds[r * HSTRIDE + l] = (xv.x + xv.y + xv.z + xv.w) * 0.25f;
            }
        }
    }
    __syncthreads();

    if (tid >= ROWS) return;
    const long long row = r0 + tid;
    if (row >= Btot) return;

    // small weights: uniform-address derefs -> scalar loads (SGPR), no VGPR cost
    const float whr0 = wh_rec[0], whr1 = wh_rec[1];
    const float wxr00 = wx_rec[0], wxr01 = wx_rec[1];
    const float wxr10 = wx_rec[2], wxr11 = wx_rec[3];
    const float we00 = wx_eval[0], we01 = wx_eval[1];
    const float we10 = wx_eval[2], we11 = wx_eval[3];
    const float whe0 = wh_eval[0], whe1 = wh_eval[1];
    const float be0 = b_eval[0], be1 = b_eval[1];

    const float* __restrict__ hr = &hlds[tid * HSTRIDE];

    // rolling state
    float ya[3][4];                    // conv partial sums, slot = p & 3 (all static idx)
    float zg[3];                       // running max of current pool group
    float lg0 = fc_b[0], lg1 = fc_b[1], lg2 = fc_b[2];   // logits accumulate as groups finish

    float c0 = 0.f, c1 = 0.f;          // scan carry
    float cur0 = 0.f, cur1 = 0.f;      // x_rec[l]   = out_{l-2}
    float prv0 = 0.f, prv1 = 0.f;      // x_rec[l-1] = out_{l-3}
    float hprev = 0.f, h0save = 0.f;
    float p0 = 0.f, p1 = 0.f, p2 = 0.f;

#pragma unroll
    for (int l = 0; l < LMAX; l++) {
        const float hl = hr[l];
        if (l == 0) h0save = hl;
        float ev0 = 0.f, ev1 = 0.f;
        if (l >= 2) {
            // scan step producing out_{l-2}; input hseq[l-2] = (l==2 ? h[0] : h[l-1])
            const float hin = (l == 2) ? h0save : hprev;
            const float n0 = fmaf(c0, wxr00, fmaf(c1, wxr10, hin * whr0));
            const float n1 = fmaf(c0, wxr01, fmaf(c1, wxr11, hin * whr1));
            prv0 = cur0; prv1 = cur1;
            cur0 = n0;   cur1 = n1;
            c0 = n0;     c1 = n1;

            const float hterm = (l == 2) ? h0save : hprev;  // h_term[l]
            const float xc0 = (l >= 3) ? cur0 : 0.f;
            const float xc1 = (l >= 3) ? cur1 : 0.f;
            const float xp0 = (l >= 4) ? prv0 : 0.f;
            const float xp1 = (l >= 4) ? prv1 : 0.f;
            ev0 = fmaf(xp0, we00, fmaf(xc0, we01, fmaf(hterm, whe0, be0)));
            ev1 = fmaf(xp1, we10, fmaf(xc1, we11, fmaf(hterm, whe1, be1)));
        }
        p0 += hl; p1 += ev0; p2 += ev1;

        if ((l & 3) == 3) {
            const int m = l >> 2;                      // compile-time (full unroll)
            const float f0m = p0 * 0.25f;
            const float f1m = p1 * 0.25f;
            const float f2m = p2 * 0.25f;
            p0 = 0.f; p1 = 0.f; p2 = 0.f;

            // contributions of f_m to conv outputs p = m-3 .. m  (k = m-p = j)
#pragma unroll
            for (int j = 0; j < 4; j++) {
                const int p = m - j;
                if (p >= 0 && p <= 19) {
                    const int s = p & 3;
#pragma unroll
                    for (int o = 0; o < 3; o++) {
                        const float t = fmaf(f0m, conv_w[o * 12 + 0 + j],
                                        fmaf(f1m, conv_w[o * 12 + 4 + j],
                                             f2m * conv_w[o * 12 + 8 + j]));
                        if (j == 0) ya[o][s] = t;
                        else        ya[o][s] += t;
                    }
                }
            }
            // conv output p_done = m-3 is now complete -> maxpool -> (tanh -> FC)
            if (m >= 3) {
                const int pd = m - 3;                  // 0..19
                const int s  = pd & 3;
                const int g  = pd / 5;
                const int q  = pd % 5;
#pragma unroll
                for (int o = 0; o < 3; o++) {
                    const float y = ya[o][s] + conv_b[o];
                    zg[o] = (q == 0) ? y : fmaxf(zg[o], y);
                }
                if (q == 4) {
#pragma unroll
                    for (int o = 0; o < 3; o++) {
                        const float vv = tanh_fast(zg[o]);
                        const int d = o * 4 + g;
                        lg0 = fmaf(vv, fc_w[d],      lg0);
                        lg1 = fmaf(vv, fc_w[12 + d], lg1);
                        lg2 = fmaf(vv, fc_w[24 + d], lg2);
                    }
                }
            }
        }
        hprev = hl;
    }

    // ---- softmax ----
    const float mx = fmaxf(lg0, fmaxf(lg1, lg2));
    const float e0 = __expf(lg0 - mx);
    const float e1 = __expf(lg1 - mx);
    const float e2 = __expf(lg2 - mx);
    const float inv = 1.f / (e0 + e1 + e2);
    out[row * 3 + 0] = e0 * inv;
    out[row * 3 + 1] = e1 * inv;
    out[row * 3 + 2] = e2 * inv;
}

extern "C" void kernel_launch(void* const* d_in, const int* in_sizes, int n_in,
                              void* d_out, int out_size, void* d_ws, size_t ws_size,
                              hipStream_t stream) {
    const float* x       = (const float*)d_in[0];
    const float* wh_rec  = (const float*)d_in[1];
    const float* wx_rec  = (const float*)d_in[2];
    const float* wx_eval = (const float*)d_in[3];
    const float* wh_eval = (const float*)d_in[4];
    const float* b_eval  = (const float*)d_in[5];
    const float* conv_w  = (const float*)d_in[6];
    const float* conv_b  = (const float*)d_in[7];
    const float* fc_w    = (const float*)d_in[8];
    const float* fc_b    = (const float*)d_in[9];
    float* out = (float*)d_out;

    const long long B = (long long)in_sizes[0] / TCOLS;
    const int nblocks = (int)((B + ROWS - 1) / ROWS);

    pde_fused_v2_kernel<<<nblocks, 256, 0, stream>>>(
        x, wh_rec, wx_rec, wx_eval, wh_eval, b_eval,
        conv_w, conv_b, fc_w, fc_b, out, B);
}